// Round 4
// baseline (594.389 us; speedup 1.0000x reference)
//
#include <hip/hip_runtime.h>
#include <math.h>

// Problem constants (match reference)
#define NUM_CLASSES 80
#define BETA 0.11f
#define POS_THR 0.5f
#define NEG_THR 0.4f
#define B_CNT 8
#define A_CNT 98304
#define G_CNT 32

#define FOCAL_BLOCKS 15360            // 15360*256 threads * 4 float4 = 62,914,560 floats exactly
#define FOCAL_STRIDE (FOCAL_BLOCKS * 256)

// ws layout:
//   [0]  float cls_sum   [4] float reg_sum   [8] float num_pos

// focal term for t=0 (background class slot), HW transcendentals only:
//   e = exp(-|x|), prob = sigmoid(x), softplus(x) = max(x,0)+log(1+e)
//   focal0 = (1-ALPHA) * prob^2 * softplus(x)
__device__ __forceinline__ float focal0(float x) {
    const float e  = __expf(-fabsf(x));
    const float op = 1.0f + e;
    const float r  = __builtin_amdgcn_rcpf(op);
    const float prob = (x >= 0.0f) ? r : e * r;
    const float sp = fmaxf(x, 0.0f) + __logf(op);
    return 0.75f * prob * prob * sp;
}

// focal term for t=1: focal1 = ALPHA * (1-prob)^2 * softplus(-x)
__device__ __forceinline__ float focal1(float x) {
    const float e  = __expf(-fabsf(x));
    const float op = 1.0f + e;
    const float r  = __builtin_amdgcn_rcpf(op);
    const float prob = (x >= 0.0f) ? r : e * r;
    const float q  = 1.0f - prob;
    const float sp = fmaxf(-x, 0.0f) + __logf(op);
    return 0.25f * q * q * sp;
}

__device__ __forceinline__ float f0x4(float4 v) {
    return (focal0(v.x) + focal0(v.y)) + (focal0(v.z) + focal0(v.w));
}

// Pure streaming reduce over ALL elements — no guards, no dependent scalar
// loads: 4 independent global_load_dwordx4 issue back-to-back per thread.
__global__ __launch_bounds__(256) void focal_kernel(
    const float* __restrict__ cls_pred,        // [B*A*80]
    float* __restrict__ accum)
{
    __shared__ float s_red[4];
    const int t = blockIdx.x * 256 + threadIdx.x;
    const float4* __restrict__ p = (const float4*)cls_pred;
    const float4 a = p[t];
    const float4 b = p[t + FOCAL_STRIDE];
    const float4 c = p[t + 2 * FOCAL_STRIDE];
    const float4 d = p[t + 3 * FOCAL_STRIDE];
    float sum = (f0x4(a) + f0x4(b)) + (f0x4(c) + f0x4(d));
    #pragma unroll
    for (int off = 32; off > 0; off >>= 1) sum += __shfl_down(sum, off, 64);
    if ((threadIdx.x & 63) == 0) s_red[threadIdx.x >> 6] = sum;
    __syncthreads();
    if (threadIdx.x == 0)
        atomicAdd(accum, (s_red[0] + s_red[1]) + (s_red[2] + s_red[3]));
}

__global__ __launch_bounds__(256) void match_kernel(
    const float* __restrict__ cls_pred,   // [B,A,80]
    const float* __restrict__ reg_pred,   // [B,A,4]
    const float* __restrict__ anchors,    // [A,4]
    const float* __restrict__ gt_boxes,   // [B,G,4]
    const int*   __restrict__ gt_labels,  // [B,G]
    float* __restrict__ accum)
{
    __shared__ float4 s_gt[G_CNT];
    __shared__ int    s_lab[G_CNT];
    __shared__ float  s_red[12];

    const int blocks_per_batch = A_CNT / 256;           // 384, exact
    const int b = blockIdx.x / blocks_per_batch;
    const int a = (blockIdx.x % blocks_per_batch) * 256 + threadIdx.x;

    if (threadIdx.x < G_CNT) {
        s_gt[threadIdx.x]  = ((const float4*)gt_boxes)[b * G_CNT + threadIdx.x];
        s_lab[threadIdx.x] = gt_labels[b * G_CNT + threadIdx.x];
    }
    __syncthreads();

    const float4 an = ((const float4*)anchors)[a];
    const float aw = an.z - an.x;
    const float ah = an.w - an.y;
    const float area_a = aw * ah;

    float best = -1.0f;
    int bidx = 0;
    #pragma unroll
    for (int g = 0; g < G_CNT; ++g) {
        const float4 gb = s_gt[g];
        const float ltx = fmaxf(an.x, gb.x);
        const float lty = fmaxf(an.y, gb.y);
        const float rbx = fminf(an.z, gb.z);
        const float rby = fminf(an.w, gb.w);
        const float w = fmaxf(rbx - ltx, 0.0f);
        const float h = fmaxf(rby - lty, 0.0f);
        const float inter = w * h;
        const float area_g = (gb.z - gb.x) * (gb.w - gb.y);
        const float iou = inter / (area_a + area_g - inter);
        if (iou > best) { best = iou; bidx = g; }   // first-max == jnp argmax
    }

    const bool pos = (best >= POS_THR);
    const bool ign = (!pos) && (best >= NEG_THR);       // cls_t == -1

    float regsum = 0.0f;
    float clsdelta = 0.0f;

    if (pos) {
        const float4 gb = s_gt[bidx];
        const float gw = gb.z - gb.x;
        const float gh = gb.w - gb.y;
        const float gx = gb.x + 0.5f * gw;
        const float gy = gb.y + 0.5f * gh;
        const float ax = an.x + 0.5f * aw;
        const float ay = an.y + 0.5f * ah;
        const float t0 = (gx - ax) / aw;
        const float t1 = (gy - ay) / ah;
        const float t2 = __logf(gw / aw);
        const float t3 = __logf(gh / ah);
        const float4 rp = ((const float4*)reg_pred)[b * A_CNT + a];
        const float d0 = fabsf(rp.x - t0);
        const float d1 = fabsf(rp.y - t1);
        const float d2 = fabsf(rp.z - t2);
        const float d3 = fabsf(rp.w - t3);
        const float s0 = (d0 < BETA) ? 0.5f * d0 * d0 / BETA : d0 - 0.5f * BETA;
        const float s1 = (d1 < BETA) ? 0.5f * d1 * d1 / BETA : d1 - 0.5f * BETA;
        const float s2 = (d2 < BETA) ? 0.5f * d2 * d2 / BETA : d2 - 0.5f * BETA;
        const float s3 = (d3 < BETA) ? 0.5f * d3 * d3 / BETA : d3 - 0.5f * BETA;
        regsum = (s0 + s1) + (s2 + s3);

        // fg correction: target-class element uses focal1 instead of focal0.
        const int lab = s_lab[bidx];                    // 1..80
        const float xt = cls_pred[(size_t)(b * A_CNT + a) * NUM_CLASSES + (lab - 1)];
        clsdelta = focal1(xt) - focal0(xt);
    } else if (ign) {
        // ignore anchor: subtract its entire 80-class focal0 row from the
        // unconditional total computed by focal_kernel.
        const float4* __restrict__ row =
            (const float4*)(cls_pred + (size_t)(b * A_CNT + a) * NUM_CLASSES);
        float s = 0.0f;
        #pragma unroll
        for (int c = 0; c < NUM_CLASSES / 4; ++c) s += f0x4(row[c]);
        clsdelta = -s;
    }

    // fused 3-value block reduction (independent shuffle chains -> ILP)
    float v0 = clsdelta;
    float v1 = regsum;
    float v2 = pos ? 1.0f : 0.0f;
    #pragma unroll
    for (int off = 32; off > 0; off >>= 1) {
        v0 += __shfl_down(v0, off, 64);
        v1 += __shfl_down(v1, off, 64);
        v2 += __shfl_down(v2, off, 64);
    }
    const int wave = threadIdx.x >> 6;
    if ((threadIdx.x & 63) == 0) {
        s_red[wave] = v0; s_red[4 + wave] = v1; s_red[8 + wave] = v2;
    }
    __syncthreads();
    if (threadIdx.x == 0) {
        const float r0 = (s_red[0] + s_red[1]) + (s_red[2] + s_red[3]);
        const float r1 = (s_red[4] + s_red[5]) + (s_red[6] + s_red[7]);
        const float r2 = (s_red[8] + s_red[9]) + (s_red[10] + s_red[11]);
        if (r0 != 0.0f) atomicAdd(&accum[0], r0);
        if (r1 != 0.0f) atomicAdd(&accum[1], r1);
        if (r2 != 0.0f) atomicAdd(&accum[2], r2);
    }
}

__global__ void finalize_kernel(const float* __restrict__ accum, float* __restrict__ out) {
    const float cs = accum[0];
    const float rs = accum[1];
    const float np = accum[2];
    const float denom = fmaxf(np, 1.0f);
    const float cl = (np > 0.0f) ? cs / denom : cs;
    const float rl = (np > 0.0f) ? rs / denom : 0.0f;
    out[0] = cl + rl;
    out[1] = cl;
    out[2] = rl;
}

extern "C" void kernel_launch(void* const* d_in, const int* in_sizes, int n_in,
                              void* d_out, int out_size, void* d_ws, size_t ws_size,
                              hipStream_t stream) {
    const float* cls_pred = (const float*)d_in[0];   // [B,A,80]
    const float* reg_pred = (const float*)d_in[1];   // [B,A,4]
    const float* anchors  = (const float*)d_in[2];   // [A,4]
    const float* gt_boxes = (const float*)d_in[3];   // [B,G,4]
    const int*   gt_labels= (const int*)d_in[4];     // [B,G]
    float* out = (float*)d_out;

    float* accum = (float*)d_ws;                     // 3 floats
    hipMemsetAsync(d_ws, 0, 16, stream);

    const int blocks1 = (B_CNT * A_CNT) / 256;       // 3072
    match_kernel<<<blocks1, 256, 0, stream>>>(cls_pred, reg_pred, anchors, gt_boxes,
                                              gt_labels, accum);

    focal_kernel<<<FOCAL_BLOCKS, 256, 0, stream>>>(cls_pred, accum);

    finalize_kernel<<<1, 1, 0, stream>>>(accum, out);
}

// Round 5
// 402.450 us; speedup vs baseline: 1.4769x; 1.4769x over previous
//
#include <hip/hip_runtime.h>
#include <math.h>

// Problem constants (match reference)
#define NUM_CLASSES 80
#define BETA 0.11f
#define POS_THR 0.5f
#define NEG_THR 0.4f
#define B_CNT 8
#define A_CNT 98304
#define G_CNT 32

// focal: 2048 blocks * 256 thr = 524288 threads; 15,728,640 float4 / 524288 = 30 each
#define FOCAL_BLOCKS 2048
#define FOCAL_STRIDE (FOCAL_BLOCKS * 256)
#define MATCH_BLOCKS ((B_CNT * A_CNT) / 256)   // 3072

// ws layout (floats) — all partials written unconditionally, no memset needed:
//   [0      .. 2048)          focal partial sums (one per focal block)
//   [2048   .. 2048+3072)     match cls-delta partials
//   [5120   .. 5120+3072)     match reg-sum partials
//   [8192   .. 8192+3072)     match pos-count partials
#define WS_FP   0
#define WS_MC   2048
#define WS_MR   (2048 + 3072)
#define WS_MP   (2048 + 2 * 3072)

// focal term for t=0 (background class slot), HW transcendentals only:
//   e = exp(-|x|), prob = sigmoid(x), softplus(x) = max(x,0)+log(1+e)
//   focal0 = (1-ALPHA) * prob^2 * softplus(x)
__device__ __forceinline__ float focal0(float x) {
    const float e  = __expf(-fabsf(x));
    const float op = 1.0f + e;
    const float r  = __builtin_amdgcn_rcpf(op);
    const float prob = (x >= 0.0f) ? r : e * r;
    const float sp = fmaxf(x, 0.0f) + __logf(op);
    return 0.75f * prob * prob * sp;
}

// focal term for t=1: focal1 = ALPHA * (1-prob)^2 * softplus(-x)
__device__ __forceinline__ float focal1(float x) {
    const float e  = __expf(-fabsf(x));
    const float op = 1.0f + e;
    const float r  = __builtin_amdgcn_rcpf(op);
    const float prob = (x >= 0.0f) ? r : e * r;
    const float q  = 1.0f - prob;
    const float sp = fmaxf(-x, 0.0f) + __logf(op);
    return 0.25f * q * q * sp;
}

__device__ __forceinline__ float f0x4(float4 v) {
    return (focal0(v.x) + focal0(v.y)) + (focal0(v.z) + focal0(v.w));
}

// Streaming reduce over ALL elements. NO atomics: one plain store per block.
__global__ __launch_bounds__(256) void focal_kernel(
    const float* __restrict__ cls_pred,        // [B*A*80]
    float* __restrict__ ws)
{
    __shared__ float s_red[4];
    const int t = blockIdx.x * 256 + threadIdx.x;
    const float4* __restrict__ p = (const float4*)cls_pred;
    float sum = 0.0f;
    // 30 float4 per thread as 5 batches of 6 independent loads
    #pragma unroll
    for (int outer = 0; outer < 5; ++outer) {
        float4 v[6];
        #pragma unroll
        for (int j = 0; j < 6; ++j)
            v[j] = p[t + (outer * 6 + j) * FOCAL_STRIDE];
        #pragma unroll
        for (int j = 0; j < 6; ++j)
            sum += f0x4(v[j]);
    }
    #pragma unroll
    for (int off = 32; off > 0; off >>= 1) sum += __shfl_down(sum, off, 64);
    if ((threadIdx.x & 63) == 0) s_red[threadIdx.x >> 6] = sum;
    __syncthreads();
    if (threadIdx.x == 0)
        ws[WS_FP + blockIdx.x] = (s_red[0] + s_red[1]) + (s_red[2] + s_red[3]);
}

__global__ __launch_bounds__(256) void match_kernel(
    const float* __restrict__ cls_pred,   // [B,A,80]
    const float* __restrict__ reg_pred,   // [B,A,4]
    const float* __restrict__ anchors,    // [A,4]
    const float* __restrict__ gt_boxes,   // [B,G,4]
    const int*   __restrict__ gt_labels,  // [B,G]
    float* __restrict__ ws)
{
    __shared__ float4 s_gt[G_CNT];
    __shared__ int    s_lab[G_CNT];
    __shared__ float  s_red[12];

    const int blocks_per_batch = A_CNT / 256;           // 384, exact
    const int b = blockIdx.x / blocks_per_batch;
    const int a = (blockIdx.x % blocks_per_batch) * 256 + threadIdx.x;

    if (threadIdx.x < G_CNT) {
        s_gt[threadIdx.x]  = ((const float4*)gt_boxes)[b * G_CNT + threadIdx.x];
        s_lab[threadIdx.x] = gt_labels[b * G_CNT + threadIdx.x];
    }
    __syncthreads();

    const float4 an = ((const float4*)anchors)[a];
    const float aw = an.z - an.x;
    const float ah = an.w - an.y;
    const float area_a = aw * ah;

    float best = -1.0f;
    int bidx = 0;
    #pragma unroll
    for (int g = 0; g < G_CNT; ++g) {
        const float4 gb = s_gt[g];
        const float ltx = fmaxf(an.x, gb.x);
        const float lty = fmaxf(an.y, gb.y);
        const float rbx = fminf(an.z, gb.z);
        const float rby = fminf(an.w, gb.w);
        const float w = fmaxf(rbx - ltx, 0.0f);
        const float h = fmaxf(rby - lty, 0.0f);
        const float inter = w * h;
        const float area_g = (gb.z - gb.x) * (gb.w - gb.y);
        const float iou = inter / (area_a + area_g - inter);
        if (iou > best) { best = iou; bidx = g; }   // first-max == jnp argmax
    }

    const bool pos = (best >= POS_THR);
    const bool ign = (!pos) && (best >= NEG_THR);       // cls_t == -1

    float regsum = 0.0f;
    float clsdelta = 0.0f;

    if (pos) {
        const float4 gb = s_gt[bidx];
        const float gw = gb.z - gb.x;
        const float gh = gb.w - gb.y;
        const float gx = gb.x + 0.5f * gw;
        const float gy = gb.y + 0.5f * gh;
        const float ax = an.x + 0.5f * aw;
        const float ay = an.y + 0.5f * ah;
        const float t0 = (gx - ax) / aw;
        const float t1 = (gy - ay) / ah;
        const float t2 = __logf(gw / aw);
        const float t3 = __logf(gh / ah);
        const float4 rp = ((const float4*)reg_pred)[b * A_CNT + a];
        const float d0 = fabsf(rp.x - t0);
        const float d1 = fabsf(rp.y - t1);
        const float d2 = fabsf(rp.z - t2);
        const float d3 = fabsf(rp.w - t3);
        const float s0 = (d0 < BETA) ? 0.5f * d0 * d0 / BETA : d0 - 0.5f * BETA;
        const float s1 = (d1 < BETA) ? 0.5f * d1 * d1 / BETA : d1 - 0.5f * BETA;
        const float s2 = (d2 < BETA) ? 0.5f * d2 * d2 / BETA : d2 - 0.5f * BETA;
        const float s3 = (d3 < BETA) ? 0.5f * d3 * d3 / BETA : d3 - 0.5f * BETA;
        regsum = (s0 + s1) + (s2 + s3);

        // fg correction: target-class element uses focal1 instead of focal0.
        const int lab = s_lab[bidx];                    // 1..80
        const float xt = cls_pred[(size_t)(b * A_CNT + a) * NUM_CLASSES + (lab - 1)];
        clsdelta = focal1(xt) - focal0(xt);
    } else if (ign) {
        // ignore anchor: subtract its entire 80-class focal0 row from the
        // unconditional total computed by focal_kernel.
        const float4* __restrict__ row =
            (const float4*)(cls_pred + (size_t)(b * A_CNT + a) * NUM_CLASSES);
        float s = 0.0f;
        #pragma unroll
        for (int c = 0; c < NUM_CLASSES / 4; ++c) s += f0x4(row[c]);
        clsdelta = -s;
    }

    // fused 3-value block reduction (independent shuffle chains -> ILP)
    float v0 = clsdelta;
    float v1 = regsum;
    float v2 = pos ? 1.0f : 0.0f;
    #pragma unroll
    for (int off = 32; off > 0; off >>= 1) {
        v0 += __shfl_down(v0, off, 64);
        v1 += __shfl_down(v1, off, 64);
        v2 += __shfl_down(v2, off, 64);
    }
    const int wave = threadIdx.x >> 6;
    if ((threadIdx.x & 63) == 0) {
        s_red[wave] = v0; s_red[4 + wave] = v1; s_red[8 + wave] = v2;
    }
    __syncthreads();
    if (threadIdx.x == 0) {
        // plain stores to per-block slots — no atomic contention
        ws[WS_MC + blockIdx.x] = (s_red[0] + s_red[1]) + (s_red[2] + s_red[3]);
        ws[WS_MR + blockIdx.x] = (s_red[4] + s_red[5]) + (s_red[6] + s_red[7]);
        ws[WS_MP + blockIdx.x] = (s_red[8] + s_red[9]) + (s_red[10] + s_red[11]);
    }
}

// Single block reduces all partials and writes the 3 outputs.
__global__ __launch_bounds__(256) void finalize_kernel(
    const float* __restrict__ ws, float* __restrict__ out)
{
    __shared__ float s_red[12];
    float c = 0.0f, r = 0.0f, np = 0.0f;
    #pragma unroll
    for (int k = 0; k < FOCAL_BLOCKS / 256; ++k)            // 8
        c += ws[WS_FP + k * 256 + threadIdx.x];
    #pragma unroll
    for (int k = 0; k < MATCH_BLOCKS / 256; ++k) {          // 12
        c  += ws[WS_MC + k * 256 + threadIdx.x];
        r  += ws[WS_MR + k * 256 + threadIdx.x];
        np += ws[WS_MP + k * 256 + threadIdx.x];
    }
    #pragma unroll
    for (int off = 32; off > 0; off >>= 1) {
        c  += __shfl_down(c,  off, 64);
        r  += __shfl_down(r,  off, 64);
        np += __shfl_down(np, off, 64);
    }
    const int wave = threadIdx.x >> 6;
    if ((threadIdx.x & 63) == 0) {
        s_red[wave] = c; s_red[4 + wave] = r; s_red[8 + wave] = np;
    }
    __syncthreads();
    if (threadIdx.x == 0) {
        const float cs = (s_red[0] + s_red[1]) + (s_red[2] + s_red[3]);
        const float rs = (s_red[4] + s_red[5]) + (s_red[6] + s_red[7]);
        const float n  = (s_red[8] + s_red[9]) + (s_red[10] + s_red[11]);
        const float denom = fmaxf(n, 1.0f);
        const float cl = (n > 0.0f) ? cs / denom : cs;
        const float rl = (n > 0.0f) ? rs / denom : 0.0f;
        out[0] = cl + rl;
        out[1] = cl;
        out[2] = rl;
    }
}

extern "C" void kernel_launch(void* const* d_in, const int* in_sizes, int n_in,
                              void* d_out, int out_size, void* d_ws, size_t ws_size,
                              hipStream_t stream) {
    const float* cls_pred = (const float*)d_in[0];   // [B,A,80]
    const float* reg_pred = (const float*)d_in[1];   // [B,A,4]
    const float* anchors  = (const float*)d_in[2];   // [A,4]
    const float* gt_boxes = (const float*)d_in[3];   // [B,G,4]
    const int*   gt_labels= (const int*)d_in[4];     // [B,G]
    float* out = (float*)d_out;
    float* ws  = (float*)d_ws;

    match_kernel<<<MATCH_BLOCKS, 256, 0, stream>>>(cls_pred, reg_pred, anchors,
                                                   gt_boxes, gt_labels, ws);
    focal_kernel<<<FOCAL_BLOCKS, 256, 0, stream>>>(cls_pred, ws);
    finalize_kernel<<<1, 256, 0, stream>>>(ws, out);
}

// Round 6
// 371.163 us; speedup vs baseline: 1.6014x; 1.0843x over previous
//
#include <hip/hip_runtime.h>
#include <math.h>

// Problem constants (match reference)
#define NUM_CLASSES 80
#define BETA 0.11f
#define POS_THR 0.5f
#define NEG_THR 0.4f
#define B_CNT 8
#define A_CNT 98304
#define G_CNT 32

// One fused kernel: 3072 blocks x 256 threads = 786432 threads.
// Focal stream: B*A*80/4 = 15,728,640 float4 / 786432 = 20 float4 per thread, exact.
#define FUSED_BLOCKS ((B_CNT * A_CNT) / 256)   // 3072
#define FUSED_STRIDE (FUSED_BLOCKS * 256)      // 786432

// ws layout (floats), plain per-block stores — no contention, no memset:
//   [0    .. 3072)  cls partials (focal sum + fg/ignore deltas)
//   [3072 .. 6144)  reg partials
//   [6144 .. 9216)  pos-count partials
#define WS_MC 0
#define WS_MR FUSED_BLOCKS
#define WS_MP (2 * FUSED_BLOCKS)

// focal term for t=0 (background slot), HW transcendentals only:
//   e = exp(-|x|), prob = sigmoid(x), softplus(x) = max(x,0)+log(1+e)
//   focal0 = (1-ALPHA) * prob^2 * softplus(x)
__device__ __forceinline__ float focal0(float x) {
    const float e  = __expf(-fabsf(x));
    const float op = 1.0f + e;
    const float r  = __builtin_amdgcn_rcpf(op);
    const float prob = (x >= 0.0f) ? r : e * r;
    const float sp = fmaxf(x, 0.0f) + __logf(op);
    return 0.75f * prob * prob * sp;
}

// focal term for t=1: focal1 = ALPHA * (1-prob)^2 * softplus(-x)
__device__ __forceinline__ float focal1(float x) {
    const float e  = __expf(-fabsf(x));
    const float op = 1.0f + e;
    const float r  = __builtin_amdgcn_rcpf(op);
    const float prob = (x >= 0.0f) ? r : e * r;
    const float q  = 1.0f - prob;
    const float sp = fmaxf(-x, 0.0f) + __logf(op);
    return 0.25f * q * q * sp;
}

__device__ __forceinline__ float f0x4(float4 v) {
    return (focal0(v.x) + focal0(v.y)) + (focal0(v.z) + focal0(v.w));
}

__global__ __launch_bounds__(256) void fused_kernel(
    const float* __restrict__ cls_pred,   // [B,A,80]
    const float* __restrict__ reg_pred,   // [B,A,4]
    const float* __restrict__ anchors,    // [A,4]
    const float* __restrict__ gt_boxes,   // [B,G,4]
    const int*   __restrict__ gt_labels,  // [B,G]
    float* __restrict__ ws)
{
    __shared__ float4 s_gt[G_CNT];
    __shared__ int    s_lab[G_CNT];
    __shared__ float  s_red[12];

    const int blocks_per_batch = A_CNT / 256;           // 384, exact
    const int b = blockIdx.x / blocks_per_batch;
    const int a = (blockIdx.x % blocks_per_batch) * 256 + threadIdx.x;

    if (threadIdx.x < G_CNT) {
        s_gt[threadIdx.x]  = ((const float4*)gt_boxes)[b * G_CNT + threadIdx.x];
        s_lab[threadIdx.x] = gt_labels[b * G_CNT + threadIdx.x];
    }
    __syncthreads();

    // ---------------- match phase ----------------
    const float4 an = ((const float4*)anchors)[a];
    const float aw = an.z - an.x;
    const float ah = an.w - an.y;
    const float area_a = aw * ah;

    float best = -1.0f;
    int bidx = 0;
    #pragma unroll
    for (int g = 0; g < G_CNT; ++g) {
        const float4 gb = s_gt[g];
        const float ltx = fmaxf(an.x, gb.x);
        const float lty = fmaxf(an.y, gb.y);
        const float rbx = fminf(an.z, gb.z);
        const float rby = fminf(an.w, gb.w);
        const float w = fmaxf(rbx - ltx, 0.0f);
        const float h = fmaxf(rby - lty, 0.0f);
        const float inter = w * h;
        const float area_g = (gb.z - gb.x) * (gb.w - gb.y);
        const float iou = inter / (area_a + area_g - inter);
        if (iou > best) { best = iou; bidx = g; }   // first-max == jnp argmax
    }

    const bool pos = (best >= POS_THR);
    const bool ign = (!pos) && (best >= NEG_THR);       // cls_t == -1

    float regsum = 0.0f;
    float clsdelta = 0.0f;

    if (pos) {
        const float4 gb = s_gt[bidx];
        const float gw = gb.z - gb.x;
        const float gh = gb.w - gb.y;
        const float gx = gb.x + 0.5f * gw;
        const float gy = gb.y + 0.5f * gh;
        const float ax = an.x + 0.5f * aw;
        const float ay = an.y + 0.5f * ah;
        const float t0 = (gx - ax) / aw;
        const float t1 = (gy - ay) / ah;
        const float t2 = __logf(gw / aw);
        const float t3 = __logf(gh / ah);
        const float4 rp = ((const float4*)reg_pred)[b * A_CNT + a];
        const float d0 = fabsf(rp.x - t0);
        const float d1 = fabsf(rp.y - t1);
        const float d2 = fabsf(rp.z - t2);
        const float d3 = fabsf(rp.w - t3);
        const float s0 = (d0 < BETA) ? 0.5f * d0 * d0 / BETA : d0 - 0.5f * BETA;
        const float s1 = (d1 < BETA) ? 0.5f * d1 * d1 / BETA : d1 - 0.5f * BETA;
        const float s2 = (d2 < BETA) ? 0.5f * d2 * d2 / BETA : d2 - 0.5f * BETA;
        const float s3 = (d3 < BETA) ? 0.5f * d3 * d3 / BETA : d3 - 0.5f * BETA;
        regsum = (s0 + s1) + (s2 + s3);

        // fg correction: target-class element uses focal1 instead of focal0.
        const int lab = s_lab[bidx];                    // 1..80
        const float xt = cls_pred[(size_t)(b * A_CNT + a) * NUM_CLASSES + (lab - 1)];
        clsdelta = focal1(xt) - focal0(xt);
    } else if (ign) {
        // ignore anchor: subtract its entire 80-class focal0 row from the
        // unconditional total below.
        const float4* __restrict__ row =
            (const float4*)(cls_pred + (size_t)(b * A_CNT + a) * NUM_CLASSES);
        float s = 0.0f;
        #pragma unroll
        for (int c = 0; c < NUM_CLASSES / 4; ++c) s += f0x4(row[c]);
        clsdelta = -s;
    }

    // ---------------- focal stream phase ----------------
    // Unconditional coalesced stream over ALL B*A*80 logits.
    const int t = blockIdx.x * 256 + threadIdx.x;
    const float4* __restrict__ p = (const float4*)cls_pred;
    float fsum = 0.0f;
    #pragma unroll
    for (int outer = 0; outer < 4; ++outer) {
        float4 v[5];
        #pragma unroll
        for (int j = 0; j < 5; ++j)
            v[j] = p[t + (outer * 5 + j) * FUSED_STRIDE];
        #pragma unroll
        for (int j = 0; j < 5; ++j)
            fsum += f0x4(v[j]);
    }

    // ---------------- fused 3-value block reduction ----------------
    float v0 = clsdelta + fsum;
    float v1 = regsum;
    float v2 = pos ? 1.0f : 0.0f;
    #pragma unroll
    for (int off = 32; off > 0; off >>= 1) {
        v0 += __shfl_down(v0, off, 64);
        v1 += __shfl_down(v1, off, 64);
        v2 += __shfl_down(v2, off, 64);
    }
    const int wave = threadIdx.x >> 6;
    if ((threadIdx.x & 63) == 0) {
        s_red[wave] = v0; s_red[4 + wave] = v1; s_red[8 + wave] = v2;
    }
    __syncthreads();
    if (threadIdx.x == 0) {
        ws[WS_MC + blockIdx.x] = (s_red[0] + s_red[1]) + (s_red[2] + s_red[3]);
        ws[WS_MR + blockIdx.x] = (s_red[4] + s_red[5]) + (s_red[6] + s_red[7]);
        ws[WS_MP + blockIdx.x] = (s_red[8] + s_red[9]) + (s_red[10] + s_red[11]);
    }
}

// Single block reduces all partials and writes the 3 outputs.
__global__ __launch_bounds__(256) void finalize_kernel(
    const float* __restrict__ ws, float* __restrict__ out)
{
    __shared__ float s_red[12];
    float c = 0.0f, r = 0.0f, np = 0.0f;
    #pragma unroll
    for (int k = 0; k < FUSED_BLOCKS / 256; ++k) {          // 12
        c  += ws[WS_MC + k * 256 + threadIdx.x];
        r  += ws[WS_MR + k * 256 + threadIdx.x];
        np += ws[WS_MP + k * 256 + threadIdx.x];
    }
    #pragma unroll
    for (int off = 32; off > 0; off >>= 1) {
        c  += __shfl_down(c,  off, 64);
        r  += __shfl_down(r,  off, 64);
        np += __shfl_down(np, off, 64);
    }
    const int wave = threadIdx.x >> 6;
    if ((threadIdx.x & 63) == 0) {
        s_red[wave] = c; s_red[4 + wave] = r; s_red[8 + wave] = np;
    }
    __syncthreads();
    if (threadIdx.x == 0) {
        const float cs = (s_red[0] + s_red[1]) + (s_red[2] + s_red[3]);
        const float rs = (s_red[4] + s_red[5]) + (s_red[6] + s_red[7]);
        const float n  = (s_red[8] + s_red[9]) + (s_red[10] + s_red[11]);
        const float denom = fmaxf(n, 1.0f);
        const float cl = (n > 0.0f) ? cs / denom : cs;
        const float rl = (n > 0.0f) ? rs / denom : 0.0f;
        out[0] = cl + rl;
        out[1] = cl;
        out[2] = rl;
    }
}

extern "C" void kernel_launch(void* const* d_in, const int* in_sizes, int n_in,
                              void* d_out, int out_size, void* d_ws, size_t ws_size,
                              hipStream_t stream) {
    const float* cls_pred = (const float*)d_in[0];   // [B,A,80]
    const float* reg_pred = (const float*)d_in[1];   // [B,A,4]
    const float* anchors  = (const float*)d_in[2];   // [A,4]
    const float* gt_boxes = (const float*)d_in[3];   // [B,G,4]
    const int*   gt_labels= (const int*)d_in[4];     // [B,G]
    float* out = (float*)d_out;
    float* ws  = (float*)d_ws;

    fused_kernel<<<FUSED_BLOCKS, 256, 0, stream>>>(cls_pred, reg_pred, anchors,
                                                   gt_boxes, gt_labels, ws);
    finalize_kernel<<<1, 256, 0, stream>>>(ws, out);
}